// Round 10
// baseline (415.519 us; speedup 1.0000x reference)
//
#include <hip/hip_runtime.h>
#include <math.h>

#define B_   2
#define L1_  4096
#define L2_  6144
#define DM_  256
#define H_   8
#define DH_  32
#define GRID_ 512   // 2 blocks/CU guaranteed resident -> custom grid barrier is safe

typedef __bf16 bf16x8 __attribute__((ext_vector_type(8)));
typedef __bf16 bf16x4 __attribute__((ext_vector_type(4)));
typedef float floatx4 __attribute__((ext_vector_type(4)));
typedef _Float16 f16;
typedef _Float16 f16x8 __attribute__((ext_vector_type(8)));
typedef __fp16 fp16v2 __attribute__((ext_vector_type(2)));

__device__ __forceinline__ bf16x8 ldb(const __bf16* p) { return *(const bf16x8*)p; }

__device__ __forceinline__ bf16x4 pack4(floatx4 v) {
    bf16x4 r;
    r[0] = (__bf16)v[0]; r[1] = (__bf16)v[1];
    r[2] = (__bf16)v[2]; r[3] = (__bf16)v[3];
    return r;
}

__device__ __forceinline__ float pkrtz(float a, float b) {
    fp16v2 p = __builtin_amdgcn_cvt_pkrtz(a, b);
    return __builtin_bit_cast(float, p);
}

__device__ __forceinline__ bf16x8 loadx8(const float* __restrict__ p) {
    float4 a = *(const float4*)p;
    float4 b = *(const float4*)(p + 4);
    bf16x8 r;
    r[0] = (__bf16)a.x; r[1] = (__bf16)a.y; r[2] = (__bf16)a.z; r[3] = (__bf16)a.w;
    r[4] = (__bf16)b.x; r[5] = (__bf16)b.y; r[6] = (__bf16)b.z; r[7] = (__bf16)b.w;
    return r;
}

// one-shot grid barrier (distinct counter per use; counters pre-zeroed via memset)
__device__ __forceinline__ void grid_barrier(unsigned int* __restrict__ ctr, unsigned int nblk) {
    __syncthreads();
    if (threadIdx.x == 0) {
        __threadfence();                                   // device-scope release
        __hip_atomic_fetch_add(ctr, 1u, __ATOMIC_ACQ_REL, __HIP_MEMORY_SCOPE_AGENT);
        while (__hip_atomic_load(ctr, __ATOMIC_ACQUIRE, __HIP_MEMORY_SCOPE_AGENT) < nblk)
            __builtin_amdgcn_s_sleep(1);
        __threadfence();                                   // device-scope acquire
    }
    __syncthreads();
}

// ---- phase 0: W fp32 -> bf16 (qscale folded into Wq); 49152 float4 ----
__device__ __forceinline__ void do_cvtW(int tid,
    const float* __restrict__ wq, const float* __restrict__ wk,
    const float* __restrict__ wv, __bf16* __restrict__ o, float qscale)
{
    if (tid >= 49152) return;
    int seg = tid >> 14;
    int off = (tid & 16383) * 4;
    const float* src = seg == 0 ? wq : (seg == 1 ? wk : wv);
    float s = seg == 0 ? qscale : 1.0f;
    float4 v = *(const float4*)(src + off);
    bf16x4 r;
    r[0] = (__bf16)(v.x * s); r[1] = (__bf16)(v.y * s);
    r[2] = (__bf16)(v.z * s); r[3] = (__bf16)(v.w * s);
    *(bf16x4*)(o + (size_t)seg * 65536 + off) = r;
}

// ---- phase 1: proj tile (32 rows x 256 cols). tile [0,256)=Q, [256,640)=K, [640,1024)=V ----
__device__ __forceinline__ void do_proj_tile(int tile,
    const float* __restrict__ x, const float* __restrict__ src,
    const __bf16* __restrict__ Wbf,
    __bf16* __restrict__ qo, __bf16* __restrict__ ko, f16* __restrict__ vo,
    f16* __restrict__ ldsV)
{
    int y, xb;
    if      (tile < 256) { y = 0; xb = tile; }
    else if (tile < 640) { y = 1; xb = tile - 256; }
    else                 { y = 2; xb = tile - 640; }

    const int L = (y == 0) ? L1_ : L2_;
    const float*  X  = (y == 0) ? x : src;
    const __bf16* Wb = Wbf + (size_t)y * 65536;

    const int lane = threadIdx.x & 63;
    const int w    = threadIdx.x >> 6;
    const int g    = lane >> 4;
    const int c    = lane & 15;
    const int mb   = xb * 32;
    const int b    = mb / L;
    const int lb   = mb - b * L;

    floatx4 acc[2][4];
#pragma unroll
    for (int s = 0; s < 2; s++)
#pragma unroll
        for (int n = 0; n < 4; n++) acc[s][n] = (floatx4){0.f, 0.f, 0.f, 0.f};

#pragma unroll
    for (int kc = 0; kc < 8; kc++) {
        bf16x8 xf0 = loadx8(X + (size_t)(mb + c) * DM_ + kc * 32 + g * 8);
        bf16x8 xf1 = loadx8(X + (size_t)(mb + 16 + c) * DM_ + kc * 32 + g * 8);
#pragma unroll
        for (int n = 0; n < 4; n++) {
            const int oc = w * 64 + n * 16 + c;
            bf16x8 wf = ldb(Wb + (size_t)oc * DM_ + kc * 32 + g * 8);
            if (y == 2) {
                acc[0][n] = __builtin_amdgcn_mfma_f32_16x16x32_bf16(xf0, wf, acc[0][n], 0, 0, 0);
                acc[1][n] = __builtin_amdgcn_mfma_f32_16x16x32_bf16(xf1, wf, acc[1][n], 0, 0, 0);
            } else {
                acc[0][n] = __builtin_amdgcn_mfma_f32_16x16x32_bf16(wf, xf0, acc[0][n], 0, 0, 0);
                acc[1][n] = __builtin_amdgcn_mfma_f32_16x16x32_bf16(wf, xf1, acc[1][n], 0, 0, 0);
            }
        }
    }

    const int bhb = b * H_;
    if (y == 2) {
#pragma unroll
        for (int s = 0; s < 2; s++)
#pragma unroll
            for (int n = 0; n < 4; n++) {
                int dg = w * 64 + (n >> 1) * 32 + (n & 1) * 16 + c;
                int ll = s * 16 + g * 4;
                float2 pr;
                pr.x = pkrtz(acc[s][n][0], acc[s][n][1]);
                pr.y = pkrtz(acc[s][n][2], acc[s][n][3]);
                *(float2*)(ldsV + (size_t)dg * 36 + ll) = pr;
            }
        __syncthreads();
        const int t = threadIdx.x;
        f16* row = vo + ((size_t)(bhb + (t >> 5)) * DH_ + (t & 31)) * (size_t)L + lb;
#pragma unroll
        for (int j = 0; j < 4; j++)
            *(f16x8*)(row + j * 8) = *(const f16x8*)(ldsV + (size_t)t * 36 + j * 8);
        __syncthreads();   // protect LDS for next tile
    } else {
        __bf16* out = (y == 0) ? qo : ko;
#pragma unroll
        for (int s = 0; s < 2; s++)
#pragma unroll
            for (int n = 0; n < 4; n++) {
                int dlo = (n & 1) * 16 + g * 4;
                int h = w * 2 + (n >> 1);
                int l = lb + s * 16 + c;
                *(bf16x4*)(out + ((size_t)(bhb + h) * (size_t)L + l) * DH_ + dlo) = pack4(acc[s][n]);
            }
    }
}

// ---- phase 2: flash attention unit (R7-exact inner loop: 64 q/wave, K reg-dbuf, fp16 P) ----
__device__ __forceinline__ void attn_step(
    const bf16x8 (&qf)[4], const bf16x8 (&kf)[4], bf16x8 (&kfN)[4],
    const __bf16* __restrict__ knext,
    const f16* __restrict__ vb0, const f16* __restrict__ vb1, int kb,
    f16* __restrict__ Pw, int g, int c,
    float (&l)[4], floatx4 (&o)[4][2])
{
    f16x8 vf[4];
    vf[0] = *(const f16x8*)(vb0 + kb);
    vf[1] = *(const f16x8*)(vb1 + kb);
    vf[2] = *(const f16x8*)(vb0 + kb + 32);
    vf[3] = *(const f16x8*)(vb1 + kb + 32);
    kfN[0] = ldb(knext);
    kfN[1] = ldb(knext + 16 * DH_);
    kfN[2] = ldb(knext + 32 * DH_);
    kfN[3] = ldb(knext + 48 * DH_);

#pragma unroll
    for (int hp = 0; hp < 2; hp++) {
#pragma unroll
        for (int hh = 0; hh < 2; hh++) {
            const int h = hp * 2 + hh;
            floatx4 s[4];
#pragma unroll
            for (int st = 0; st < 4; st++)
                s[st] = __builtin_amdgcn_mfma_f32_16x16x32_bf16(
                            kf[st], qf[h], (floatx4){0.f, 0.f, 0.f, 0.f}, 0, 0, 0);
#pragma unroll
            for (int st = 0; st < 4; st++) {
                float e0 = __builtin_amdgcn_exp2f(s[st][0]);
                float e1 = __builtin_amdgcn_exp2f(s[st][1]);
                float e2 = __builtin_amdgcn_exp2f(s[st][2]);
                float e3 = __builtin_amdgcn_exp2f(s[st][3]);
                l[h] += (e0 + e1) + (e2 + e3);
                float2 pr;
                pr.x = pkrtz(e0, e1);
                pr.y = pkrtz(e2, e3);
                *(float2*)(Pw + hh * 1024 + ((st * 2 + (g >> 1)) * 16 + c) * 8 + (g & 1) * 4) = pr;
            }
        }
#pragma unroll
        for (int kc = 0; kc < 2; kc++)
#pragma unroll
            for (int hh = 0; hh < 2; hh++) {
                const int h = hp * 2 + hh;
                f16x8 pa = *(const f16x8*)(Pw + hh * 1024 + ((kc * 4 + g) * 16 + c) * 8);
                o[h][0] = __builtin_amdgcn_mfma_f32_16x16x32_f16(pa, vf[kc * 2 + 0], o[h][0], 0, 0, 0);
                o[h][1] = __builtin_amdgcn_mfma_f32_16x16x32_f16(pa, vf[kc * 2 + 1], o[h][1], 0, 0, 0);
            }
    }
}

template<bool DIRECT>
__device__ __forceinline__ void do_attn_unit(int work, int klen,
    const __bf16* __restrict__ Q, const __bf16* __restrict__ K,
    const f16* __restrict__ VT, float* __restrict__ out,
    f16* __restrict__ Opart, float* __restrict__ Lpart, f16* __restrict__ lds)
{
    const int xb = work & 15;
    const int bh = (work >> 4) & 15;
    const int z  = work >> 8;

    const int lane  = threadIdx.x & 63;
    const int w     = threadIdx.x >> 6;
    const int g     = lane >> 4;
    const int c     = lane & 15;
    const int qbase = xb * 256 + w * 64;
    const int k0    = z * klen;

    bf16x8 qf[4];
#pragma unroll
    for (int h = 0; h < 4; h++)
        qf[h] = ldb(Q + ((size_t)bh * L1_ + qbase + h * 16 + c) * DH_ + g * 8);

    const __bf16* kbase = K  + (size_t)bh * L2_ * DH_ + (size_t)c * DH_ + g * 8;
    const f16*    vb0   = VT + ((size_t)bh * DH_ + c)      * L2_ + g * 8;
    const f16*    vb1   = VT + ((size_t)bh * DH_ + 16 + c) * L2_ + g * 8;
    f16* Pw = lds + w * 2048;

    float l[4] = {0.f, 0.f, 0.f, 0.f};
    floatx4 o[4][2];
#pragma unroll
    for (int h = 0; h < 4; h++) { o[h][0] = (floatx4){0.f,0.f,0.f,0.f}; o[h][1] = (floatx4){0.f,0.f,0.f,0.f}; }

    bf16x8 kfA[4], kfB[4];
#pragma unroll
    for (int st = 0; st < 4; st++)
        kfA[st] = ldb(kbase + (size_t)(k0 + st * 16) * DH_);

    for (int t = 0; t < klen; t += 128) {
        int kb = k0 + t;
        attn_step(qf, kfA, kfB, kbase + (size_t)(kb + 64) * DH_,
                  vb0, vb1, kb, Pw, g, c, l, o);
        int nn = (t + 128 < klen) ? kb + 128 : k0;
        attn_step(qf, kfB, kfA, kbase + (size_t)nn * DH_,
                  vb0, vb1, kb + 64, Pw, g, c, l, o);
    }

#pragma unroll
    for (int h = 0; h < 4; h++) {
        l[h] += __shfl_xor(l[h], 16, 64);
        l[h] += __shfl_xor(l[h], 32, 64);
    }

    const int b  = bh / H_;
    const int hh = bh % H_;
    if (DIRECT) {
#pragma unroll
        for (int h = 0; h < 4; h++)
#pragma unroll
            for (int r = 0; r < 4; r++) {
                float lr  = __shfl(l[h], g * 4 + r, 64);
                float inv = 1.0f / lr;
                size_t base = ((size_t)(b * L1_ + qbase + h * 16 + g * 4 + r)) * DM_ + hh * DH_;
                out[base + c]      = o[h][0][r] * inv;
                out[base + 16 + c] = o[h][1][r] * inv;
            }
    } else {
        f16* Op = Opart + (size_t)z * ((size_t)B_ * L1_ * DM_);
#pragma unroll
        for (int h = 0; h < 4; h++) {
#pragma unroll
            for (int r = 0; r < 4; r++) {
                size_t base = ((size_t)(b * L1_ + qbase + h * 16 + g * 4 + r)) * DM_ + hh * DH_;
                Op[base + c]      = (f16)o[h][0][r];
                Op[base + 16 + c] = (f16)o[h][1][r];
            }
            if (g == 0)
                Lpart[(size_t)z * ((size_t)B_ * H_ * L1_) +
                      (size_t)bh * L1_ + qbase + h * 16 + c] = l[h];
        }
    }
}

// ---- phase 3: combine ----
__device__ __forceinline__ void do_combine(int t, int split,
    const f16* __restrict__ Opart, const float* __restrict__ Lpart,
    float* __restrict__ out)
{
    int row = t >> 5;             // b*L1 + q
    int col = (t & 31) * 8;       // dm
    int b   = row >> 12;
    int q   = row & (L1_ - 1);
    int bh  = b * H_ + (col >> 5);
    float a[8] = {0.f,0.f,0.f,0.f,0.f,0.f,0.f,0.f};
    float ls = 0.f;
    for (int z = 0; z < split; z++) {
        const f16* Op = Opart + (size_t)z * ((size_t)B_ * L1_ * DM_);
        f16x8 v = *(const f16x8*)(Op + (size_t)row * DM_ + col);
#pragma unroll
        for (int j = 0; j < 8; j++) a[j] += (float)v[j];
        ls += Lpart[(size_t)z * ((size_t)B_ * H_ * L1_) + (size_t)bh * L1_ + q];
    }
    float inv = 1.0f / ls;
    float4 r0, r1;
    r0.x = a[0]*inv; r0.y = a[1]*inv; r0.z = a[2]*inv; r0.w = a[3]*inv;
    r1.x = a[4]*inv; r1.y = a[5]*inv; r1.z = a[6]*inv; r1.w = a[7]*inv;
    *(float4*)(out + (size_t)row * DM_ + col)     = r0;
    *(float4*)(out + (size_t)row * DM_ + col + 4) = r1;
}

// ---- the mega kernel: all phases, 3 grid barriers, 1 launch ----
__global__ __launch_bounds__(256, 2) void mega_kernel(
    const float* __restrict__ x, const float* __restrict__ src,
    const float* __restrict__ Wq, const float* __restrict__ Wk,
    const float* __restrict__ Wv, float* __restrict__ out,
    __bf16* __restrict__ wbf, __bf16* __restrict__ qws, __bf16* __restrict__ kws,
    f16* __restrict__ vt, f16* __restrict__ Opart, float* __restrict__ Lpart,
    unsigned int* __restrict__ bar, int split, int klen, float qscale)
{
    __shared__ f16 lds[256 * 36];   // 18 KB union: proj-V transpose / attn P tiles
    const int bid = blockIdx.x;

    do_cvtW(bid * 256 + threadIdx.x, Wq, Wk, Wv, wbf, qscale);
    grid_barrier(bar + 0, GRID_);

    do_proj_tile(bid,        x, src, wbf, qws, kws, vt, lds);
    do_proj_tile(bid + 512,  x, src, wbf, qws, kws, vt, lds);
    grid_barrier(bar + 1, GRID_);

    const int units = split / 2;   // attn units per block (256*split total)
#pragma unroll 1
    for (int i = 0; i < units; i++) {
        int work = (bid & 7) * (32 * split) + (bid >> 3) + i * 64;
        do_attn_unit<false>(work, klen, qws, kws, vt, nullptr, Opart, Lpart, lds);
    }
    grid_barrier(bar + 2, GRID_);

    do_combine(bid * 256 + threadIdx.x, split, Opart, Lpart, out);
    do_combine((bid + 512) * 256 + threadIdx.x, split, Opart, Lpart, out);
}

// ---- fallback multi-kernel path (only if workspace too small for mega split>=4) ----
__global__ __launch_bounds__(256) void cvtW_kernel(
    const float* __restrict__ wq, const float* __restrict__ wk,
    const float* __restrict__ wv, __bf16* __restrict__ o, float qscale)
{
    do_cvtW(blockIdx.x * 256 + threadIdx.x, wq, wk, wv, o, qscale);
}

__global__ __launch_bounds__(256) void proj_kernel(
    const float* __restrict__ x, const float* __restrict__ src,
    const __bf16* __restrict__ Wbf,
    __bf16* __restrict__ qo, __bf16* __restrict__ ko, f16* __restrict__ vo)
{
    __shared__ f16 lds[256 * 36];
    do_proj_tile(blockIdx.x, x, src, Wbf, qo, ko, vo, lds);
}

__global__ __launch_bounds__(256, 2) void attn_direct_kernel(
    const __bf16* __restrict__ Q, const __bf16* __restrict__ K,
    const f16* __restrict__ VT, float* __restrict__ out)
{
    __shared__ f16 lds[8192];
    int bid = blockIdx.x;                       // 256
    int work = (bid & 7) * 32 + (bid >> 3);
    do_attn_unit<true>(work, L2_, Q, K, VT, out, nullptr, nullptr, lds);
}

extern "C" void kernel_launch(void* const* d_in, const int* in_sizes, int n_in,
                              void* d_out, int out_size, void* d_ws, size_t ws_size,
                              hipStream_t stream) {
    const float* x   = (const float*)d_in[0];
    const float* src = (const float*)d_in[1];
    const float* Wq  = (const float*)d_in[2];
    const float* Wk  = (const float*)d_in[3];
    const float* Wv  = (const float*)d_in[4];
    float* out = (float*)d_out;

    const float qscale = 1.4426950408889634f / sqrtf((float)DH_); // log2e * Dh^-0.5

    const size_t nW = 3 * 65536;
    const size_t nQ = (size_t)B_ * H_ * L1_ * DH_;   // 2,097,152
    const size_t nK = (size_t)B_ * H_ * L2_ * DH_;   // 3,145,728

    __bf16* wbf = (__bf16*)d_ws;
    __bf16* qws = wbf + nW;
    __bf16* kws = qws + nQ;
    f16*    vt  = (f16*)(kws + nK);
    size_t tailOff = ((nW + nQ + 2 * nK) * 2 + 255) & ~(size_t)255;

    // barrier counters: 256-byte reserved slot at tailOff; Opart/Lpart after
    unsigned int* bar = (unsigned int*)((char*)d_ws + tailOff);
    size_t dataOff = tailOff + 256;

    const size_t oPartB = (size_t)B_ * L1_ * DM_ * sizeof(f16);   // 4 MB / split
    const size_t lPartB = (size_t)B_ * H_ * L1_ * 4;              // 256 KB / split
    const size_t avail  = ws_size > dataOff ? ws_size - dataOff : 0;
    int split = 0;
    if      (avail >= 8 * (oPartB + lPartB)) split = 8;
    else if (avail >= 4 * (oPartB + lPartB)) split = 4;
    f16*   Opart = (f16*)((char*)d_ws + dataOff);
    float* Lpart = (float*)((char*)d_ws + dataOff + (size_t)split * oPartB);

    if (split) {
        hipMemsetAsync(bar, 0, 3 * sizeof(unsigned int), stream);
        mega_kernel<<<dim3(GRID_), 256, 0, stream>>>(
            x, src, Wq, Wk, Wv, out, wbf, qws, kws, vt,
            Opart, Lpart, bar, split, L2_ / split, qscale);
    } else {
        cvtW_kernel<<<dim3(192), 256, 0, stream>>>(Wq, Wk, Wv, wbf, qscale);
        proj_kernel<<<dim3(1024), 256, 0, stream>>>(x, src, wbf, qws, kws, vt);
        attn_direct_kernel<<<dim3(256), 256, 0, stream>>>(qws, kws, vt, out);
    }
}

// Round 11
// 195.235 us; speedup vs baseline: 2.1283x; 2.1283x over previous
//
#include <hip/hip_runtime.h>
#include <math.h>

#define B_   2
#define L1_  4096
#define L2_  6144
#define DM_  256
#define H_   8
#define DH_  32

typedef __bf16 bf16x8 __attribute__((ext_vector_type(8)));
typedef __bf16 bf16x4 __attribute__((ext_vector_type(4)));
typedef float floatx4 __attribute__((ext_vector_type(4)));
typedef _Float16 f16;
typedef _Float16 f16x4 __attribute__((ext_vector_type(4)));
typedef _Float16 f16x8 __attribute__((ext_vector_type(8)));
typedef __fp16 fp16v2 __attribute__((ext_vector_type(2)));

__device__ __forceinline__ bf16x8 ldb(const __bf16* p) { return *(const bf16x8*)p; }

__device__ __forceinline__ bf16x4 pack4(floatx4 v) {
    bf16x4 r;
    r[0] = (__bf16)v[0]; r[1] = (__bf16)v[1];
    r[2] = (__bf16)v[2]; r[3] = (__bf16)v[3];
    return r;
}

__device__ __forceinline__ float pkrtz(float a, float b) {
    fp16v2 p = __builtin_amdgcn_cvt_pkrtz(a, b);
    return __builtin_bit_cast(float, p);
}

// ---- convert W (qscale folded into Wq), x, source to bf16. Pure bandwidth. ----
__global__ __launch_bounds__(256) void cvt_all(
    const float* __restrict__ wq, const float* __restrict__ wk,
    const float* __restrict__ wv, const float* __restrict__ x,
    const float* __restrict__ src,
    __bf16* __restrict__ wbf, __bf16* __restrict__ xbf, __bf16* __restrict__ sbf,
    float qscale)
{
    int i = blockIdx.x * 256 + threadIdx.x;
    const float* s; __bf16* d; float sc = 1.0f; size_t off;
    if (i < 49152) {
        int seg = i >> 14;
        off = (size_t)(i & 16383) * 4;
        s = seg == 0 ? wq : (seg == 1 ? wk : wv);
        d = wbf + (size_t)seg * 65536;
        if (seg == 0) sc = qscale;
    } else if (i < 49152 + 524288) {
        off = (size_t)(i - 49152) * 4; s = x; d = xbf;
    } else {
        off = (size_t)(i - 49152 - 524288) * 4; s = src; d = sbf;
    }
    float4 v = *(const float4*)(s + off);
    bf16x4 r;
    r[0] = (__bf16)(v.x * sc); r[1] = (__bf16)(v.y * sc);
    r[2] = (__bf16)(v.z * sc); r[3] = (__bf16)(v.w * sc);
    *(bf16x4*)(d + off) = r;
}

// ---- proj: all-bf16 GEMM; Q/K out bf16, V out fp16 (transposed via LDS). ----
__global__ __launch_bounds__(256) void proj_kernel(
    const __bf16* __restrict__ xbf, const __bf16* __restrict__ sbf,
    const __bf16* __restrict__ Wbf,
    __bf16* __restrict__ qo, __bf16* __restrict__ ko, f16* __restrict__ vo)
{
    __shared__ f16 ldsV[256 * 36];   // 18 KB, V blocks only

    const int bid = blockIdx.x;
    int y, xb;
    if      (bid < 256) { y = 0; xb = bid; }
    else if (bid < 640) { y = 1; xb = bid - 256; }
    else                { y = 2; xb = bid - 640; }

    const int L = (y == 0) ? L1_ : L2_;
    const __bf16* X   = (y == 0) ? xbf : sbf;
    const __bf16* Wb  = Wbf + (size_t)y * 65536;

    const int lane = threadIdx.x & 63;
    const int w    = threadIdx.x >> 6;
    const int g    = lane >> 4;
    const int c    = lane & 15;
    const int mb   = xb * 32;
    const int b    = mb / L;
    const int lb   = mb - b * L;

    floatx4 acc[2][4];
#pragma unroll
    for (int s = 0; s < 2; s++)
#pragma unroll
        for (int n = 0; n < 4; n++) acc[s][n] = (floatx4){0.f, 0.f, 0.f, 0.f};

#pragma unroll
    for (int kc = 0; kc < 8; kc++) {
        bf16x8 xf0 = ldb(X + (size_t)(mb + c) * DM_ + kc * 32 + g * 8);
        bf16x8 xf1 = ldb(X + (size_t)(mb + 16 + c) * DM_ + kc * 32 + g * 8);
#pragma unroll
        for (int n = 0; n < 4; n++) {
            const int oc = w * 64 + n * 16 + c;
            bf16x8 wf = ldb(Wb + (size_t)oc * DM_ + kc * 32 + g * 8);
            if (y == 2) {
                acc[0][n] = __builtin_amdgcn_mfma_f32_16x16x32_bf16(xf0, wf, acc[0][n], 0, 0, 0);
                acc[1][n] = __builtin_amdgcn_mfma_f32_16x16x32_bf16(xf1, wf, acc[1][n], 0, 0, 0);
            } else {
                acc[0][n] = __builtin_amdgcn_mfma_f32_16x16x32_bf16(wf, xf0, acc[0][n], 0, 0, 0);
                acc[1][n] = __builtin_amdgcn_mfma_f32_16x16x32_bf16(wf, xf1, acc[1][n], 0, 0, 0);
            }
        }
    }

    const int bhb = b * H_;
    if (y == 2) {
        // stage [d_global][l_local] fp16 in LDS, then row-copy to VT
#pragma unroll
        for (int s = 0; s < 2; s++)
#pragma unroll
            for (int n = 0; n < 4; n++) {
                int dg = w * 64 + (n >> 1) * 32 + (n & 1) * 16 + c;
                int ll = s * 16 + g * 4;
                float2 pr;
                pr.x = pkrtz(acc[s][n][0], acc[s][n][1]);
                pr.y = pkrtz(acc[s][n][2], acc[s][n][3]);
                *(float2*)(ldsV + (size_t)dg * 36 + ll) = pr;
            }
        __syncthreads();
        const int t = threadIdx.x;
        f16* row = vo + ((size_t)(bhb + (t >> 5)) * DH_ + (t & 31)) * (size_t)L + lb;
#pragma unroll
        for (int j = 0; j < 4; j++)
            *(f16x8*)(row + j * 8) = *(const f16x8*)(ldsV + (size_t)t * 36 + j * 8);
    } else {
        __bf16* out = (y == 0) ? qo : ko;
#pragma unroll
        for (int s = 0; s < 2; s++)
#pragma unroll
            for (int n = 0; n < 4; n++) {
                int dlo = (n & 1) * 16 + g * 4;
                int h = w * 2 + (n >> 1);
                int l = lb + s * 16 + c;
                *(bf16x4*)(out + ((size_t)(bhb + h) * (size_t)L + l) * DH_ + dlo) = pack4(acc[s][n]);
            }
    }
}

// ---- flash attention: 64 q/wave, fp16 P, h-paired LDS, split-K.
// R11 change vs R7: NO explicit K/V register double-buffer — kf/vf loaded at
// tile top. Saves ~16-32 regs -> target 4 waves/SIMD (occupancy covers latency).
template<bool DIRECT>
__global__ __launch_bounds__(256, 2) void attn_kernel(
    const __bf16* __restrict__ Q, const __bf16* __restrict__ K,
    const f16* __restrict__ VT, float* __restrict__ out,
    f16* __restrict__ Opart, float* __restrict__ Lpart, int klen, int split)
{
    __shared__ f16 ldsP[4][2][1024];   // [wave][h-parity], wave-private, 16 KB

    const int bid  = blockIdx.x;
    const int work = (bid & 7) * (32 * split) + (bid >> 3);
    const int xb   = work & 15;
    const int bh   = (work >> 4) & 15;
    const int z    = work >> 8;

    const int lane  = threadIdx.x & 63;
    const int w     = threadIdx.x >> 6;
    const int g     = lane >> 4;
    const int c     = lane & 15;
    const int qbase = xb * 256 + w * 64;
    const int k0    = z * klen;

    bf16x8 qf[4];
#pragma unroll
    for (int h = 0; h < 4; h++)
        qf[h] = ldb(Q + ((size_t)bh * L1_ + qbase + h * 16 + c) * DH_ + g * 8);

    const __bf16* kbase = K  + (size_t)bh * L2_ * DH_ + (size_t)c * DH_ + g * 8;
    const f16*    vb0   = VT + ((size_t)bh * DH_ + c)      * L2_ + g * 8;
    const f16*    vb1   = VT + ((size_t)bh * DH_ + 16 + c) * L2_ + g * 8;
    f16* Pw = &ldsP[w][0][0];

    float l[4] = {0.f, 0.f, 0.f, 0.f};
    floatx4 o[4][2];
#pragma unroll
    for (int h = 0; h < 4; h++) { o[h][0] = (floatx4){0.f,0.f,0.f,0.f}; o[h][1] = (floatx4){0.f,0.f,0.f,0.f}; }

#pragma unroll 1
    for (int t = 0; t < klen; t += 64) {
        const int kb = k0 + t;
        bf16x8 kf[4];
        kf[0] = ldb(kbase + (size_t)kb * DH_);
        kf[1] = ldb(kbase + (size_t)(kb + 16) * DH_);
        kf[2] = ldb(kbase + (size_t)(kb + 32) * DH_);
        kf[3] = ldb(kbase + (size_t)(kb + 48) * DH_);
        f16x8 vf[4];
        vf[0] = *(const f16x8*)(vb0 + kb);
        vf[1] = *(const f16x8*)(vb1 + kb);
        vf[2] = *(const f16x8*)(vb0 + kb + 32);
        vf[3] = *(const f16x8*)(vb1 + kb + 32);

#pragma unroll
        for (int hp = 0; hp < 2; hp++) {
#pragma unroll
            for (int hh = 0; hh < 2; hh++) {
                const int h = hp * 2 + hh;
                floatx4 s[4];
#pragma unroll
                for (int st = 0; st < 4; st++)
                    s[st] = __builtin_amdgcn_mfma_f32_16x16x32_bf16(
                                kf[st], qf[h], (floatx4){0.f, 0.f, 0.f, 0.f}, 0, 0, 0);
#pragma unroll
                for (int st = 0; st < 4; st++) {
                    float e0 = __builtin_amdgcn_exp2f(s[st][0]);
                    float e1 = __builtin_amdgcn_exp2f(s[st][1]);
                    float e2 = __builtin_amdgcn_exp2f(s[st][2]);
                    float e3 = __builtin_amdgcn_exp2f(s[st][3]);
                    l[h] += (e0 + e1) + (e2 + e3);
                    float2 pr;
                    pr.x = pkrtz(e0, e1);
                    pr.y = pkrtz(e2, e3);
                    *(float2*)(Pw + hh * 1024 + ((st * 2 + (g >> 1)) * 16 + c) * 8 + (g & 1) * 4) = pr;
                }
            }
#pragma unroll
            for (int kc = 0; kc < 2; kc++)
#pragma unroll
                for (int hh = 0; hh < 2; hh++) {
                    const int h = hp * 2 + hh;
                    f16x8 pa = *(const f16x8*)(Pw + hh * 1024 + ((kc * 4 + g) * 16 + c) * 8);
                    o[h][0] = __builtin_amdgcn_mfma_f32_16x16x32_f16(pa, vf[kc * 2 + 0], o[h][0], 0, 0, 0);
                    o[h][1] = __builtin_amdgcn_mfma_f32_16x16x32_f16(pa, vf[kc * 2 + 1], o[h][1], 0, 0, 0);
                }
        }
    }

#pragma unroll
    for (int h = 0; h < 4; h++) {
        l[h] += __shfl_xor(l[h], 16, 64);
        l[h] += __shfl_xor(l[h], 32, 64);
    }

    const int b  = bh / H_;
    const int hh = bh % H_;
    if (DIRECT) {
#pragma unroll
        for (int h = 0; h < 4; h++)
#pragma unroll
            for (int r = 0; r < 4; r++) {
                float lr  = __shfl(l[h], g * 4 + r, 64);
                float inv = 1.0f / lr;
                size_t base = ((size_t)(b * L1_ + qbase + h * 16 + g * 4 + r)) * DM_ + hh * DH_;
                out[base + c]      = o[h][0][r] * inv;
                out[base + 16 + c] = o[h][1][r] * inv;
            }
    } else {
        f16* Op = Opart + (size_t)z * ((size_t)B_ * L1_ * DM_);
#pragma unroll
        for (int h = 0; h < 4; h++) {
#pragma unroll
            for (int r = 0; r < 4; r++) {
                size_t base = ((size_t)(b * L1_ + qbase + h * 16 + g * 4 + r)) * DM_ + hh * DH_;
                Op[base + c]      = (f16)o[h][0][r];
                Op[base + 16 + c] = (f16)o[h][1][r];
            }
            if (g == 0)
                Lpart[(size_t)z * ((size_t)B_ * H_ * L1_) +
                      (size_t)bh * L1_ + qbase + h * 16 + c] = l[h];
        }
    }
}

// out = (sum_z Opart) / (sum_z Lpart)
__global__ __launch_bounds__(256) void combine_kernel(
    const f16* __restrict__ Opart, const float* __restrict__ Lpart,
    float* __restrict__ out, int split)
{
    int t   = blockIdx.x * 256 + threadIdx.x;
    int row = t >> 6;
    int col = (t & 63) * 4;
    int b   = row >> 12;
    int q   = row & (L1_ - 1);
    int bh  = b * H_ + (col >> 5);
    float4 a = {0.f, 0.f, 0.f, 0.f};
    float ls = 0.f;
    for (int z = 0; z < split; z++) {
        const f16* Op = Opart + (size_t)z * ((size_t)B_ * L1_ * DM_);
        f16x4 v = *(const f16x4*)(Op + (size_t)row * DM_ + col);
        a.x += (float)v[0]; a.y += (float)v[1];
        a.z += (float)v[2]; a.w += (float)v[3];
        ls += Lpart[(size_t)z * ((size_t)B_ * H_ * L1_) + (size_t)bh * L1_ + q];
    }
    float inv = 1.0f / ls;
    float4 r; r.x = a.x * inv; r.y = a.y * inv; r.z = a.z * inv; r.w = a.w * inv;
    *(float4*)(out + (size_t)row * DM_ + col) = r;
}

extern "C" void kernel_launch(void* const* d_in, const int* in_sizes, int n_in,
                              void* d_out, int out_size, void* d_ws, size_t ws_size,
                              hipStream_t stream) {
    const float* x   = (const float*)d_in[0];
    const float* src = (const float*)d_in[1];
    const float* Wq  = (const float*)d_in[2];
    const float* Wk  = (const float*)d_in[3];
    const float* Wv  = (const float*)d_in[4];
    float* out = (float*)d_out;

    const float qscale = 1.4426950408889634f / sqrtf((float)DH_); // log2e * Dh^-0.5

    const size_t nW = 3 * 65536;
    const size_t nQ = (size_t)B_ * H_ * L1_ * DH_;   // 2,097,152
    const size_t nK = (size_t)B_ * H_ * L2_ * DH_;   // 3,145,728
    const size_t nX = nQ;

    // persistent: [W | Q | K | VT], union region: phase1 xbf/sbf, phase2 Opart/Lpart
    __bf16* wbf = (__bf16*)d_ws;
    __bf16* qws = wbf + nW;
    __bf16* kws = qws + nQ;
    f16*    vt  = (f16*)(kws + nK);
    size_t unionOff = ((nW + nQ + 2 * nK) * 2 + 255) & ~(size_t)255;
    __bf16* xbf = (__bf16*)((char*)d_ws + unionOff);
    __bf16* sbf = xbf + nX;

    const size_t oPartB = (size_t)B_ * L1_ * DM_ * sizeof(f16);   // 4 MB / split
    const size_t lPartB = (size_t)B_ * H_ * L1_ * 4;              // 256 KB / split
    const size_t avail  = ws_size > unionOff ? ws_size - unionOff : 0;
    int split = 1;
    if      (avail >= 8 * (oPartB + lPartB)) split = 8;
    else if (avail >= 6 * (oPartB + lPartB)) split = 6;
    else if (avail >= 4 * (oPartB + lPartB)) split = 4;
    else if (avail >= 2 * (oPartB + lPartB)) split = 2;
    f16*   Opart = (f16*)((char*)d_ws + unionOff);
    float* Lpart = (float*)((char*)d_ws + unionOff + (size_t)split * oPartB);

    cvt_all<<<dim3(5312), 256, 0, stream>>>(Wq, Wk, Wv, x, src, wbf, xbf, sbf, qscale);
    proj_kernel<<<dim3(1024), 256, 0, stream>>>(xbf, sbf, wbf, qws, kws, vt);

    if (split > 1) {
        attn_kernel<false><<<dim3(256 * split), 256, 0, stream>>>(
            qws, kws, vt, nullptr, Opart, Lpart, L2_ / split, split);
        combine_kernel<<<dim3(2048), 256, 0, stream>>>(Opart, Lpart, out, split);
    } else {
        attn_kernel<true><<<dim3(256), 256, 0, stream>>>(
            qws, kws, vt, out, nullptr, nullptr, L2_, 1);
    }
}

// Round 12
// 188.332 us; speedup vs baseline: 2.2063x; 1.0367x over previous
//
#include <hip/hip_runtime.h>
#include <math.h>

#define B_   2
#define L1_  4096
#define L2_  6144
#define DM_  256
#define H_   8
#define DH_  32

typedef __bf16 bf16x8 __attribute__((ext_vector_type(8)));
typedef __bf16 bf16x4 __attribute__((ext_vector_type(4)));
typedef float floatx4 __attribute__((ext_vector_type(4)));
typedef _Float16 f16;
typedef _Float16 f16x4 __attribute__((ext_vector_type(4)));
typedef _Float16 f16x8 __attribute__((ext_vector_type(8)));
typedef __fp16 fp16v2 __attribute__((ext_vector_type(2)));   // cvt_pkrtz return type

__device__ __forceinline__ bf16x8 ldb(const __bf16* p) { return *(const bf16x8*)p; }

__device__ __forceinline__ bf16x4 pack4(floatx4 v) {
    bf16x4 r;
    r[0] = (__bf16)v[0]; r[1] = (__bf16)v[1];
    r[2] = (__bf16)v[2]; r[3] = (__bf16)v[3];
    return r;
}

__device__ __forceinline__ float pkrtz(float a, float b) {
    fp16v2 p = __builtin_amdgcn_cvt_pkrtz(a, b);
    return __builtin_bit_cast(float, p);
}

// ---- convert W (qscale folded into Wq), x, source to bf16. Pure bandwidth. ----
__global__ __launch_bounds__(256) void cvt_all(
    const float* __restrict__ wq, const float* __restrict__ wk,
    const float* __restrict__ wv, const float* __restrict__ x,
    const float* __restrict__ src,
    __bf16* __restrict__ wbf, __bf16* __restrict__ xbf, __bf16* __restrict__ sbf,
    float qscale)
{
    int i = blockIdx.x * 256 + threadIdx.x;
    const float* s; __bf16* d; float sc = 1.0f; size_t off;
    if (i < 49152) {
        int seg = i >> 14;
        off = (size_t)(i & 16383) * 4;
        s = seg == 0 ? wq : (seg == 1 ? wk : wv);
        d = wbf + (size_t)seg * 65536;
        if (seg == 0) sc = qscale;
    } else if (i < 49152 + 524288) {
        off = (size_t)(i - 49152) * 4; s = x; d = xbf;
    } else {
        off = (size_t)(i - 49152 - 524288) * 4; s = src; d = sbf;
    }
    float4 v = *(const float4*)(s + off);
    bf16x4 r;
    r[0] = (__bf16)(v.x * sc); r[1] = (__bf16)(v.y * sc);
    r[2] = (__bf16)(v.z * sc); r[3] = (__bf16)(v.w * sc);
    *(bf16x4*)(d + off) = r;
}

// ---- proj: all-bf16 GEMM; Q/K out bf16, V out fp16 (transposed via LDS). ----
__global__ __launch_bounds__(256) void proj_kernel(
    const __bf16* __restrict__ xbf, const __bf16* __restrict__ sbf,
    const __bf16* __restrict__ Wbf,
    __bf16* __restrict__ qo, __bf16* __restrict__ ko, f16* __restrict__ vo)
{
    __shared__ f16 ldsV[256 * 36];   // 18 KB, V blocks only

    const int bid = blockIdx.x;
    int y, xb;
    if      (bid < 256) { y = 0; xb = bid; }
    else if (bid < 640) { y = 1; xb = bid - 256; }
    else                { y = 2; xb = bid - 640; }

    const int L = (y == 0) ? L1_ : L2_;
    const __bf16* X   = (y == 0) ? xbf : sbf;
    const __bf16* Wb  = Wbf + (size_t)y * 65536;

    const int lane = threadIdx.x & 63;
    const int w    = threadIdx.x >> 6;
    const int g    = lane >> 4;
    const int c    = lane & 15;
    const int mb   = xb * 32;
    const int b    = mb / L;
    const int lb   = mb - b * L;

    floatx4 acc[2][4];
#pragma unroll
    for (int s = 0; s < 2; s++)
#pragma unroll
        for (int n = 0; n < 4; n++) acc[s][n] = (floatx4){0.f, 0.f, 0.f, 0.f};

#pragma unroll
    for (int kc = 0; kc < 8; kc++) {
        bf16x8 xf0 = ldb(X + (size_t)(mb + c) * DM_ + kc * 32 + g * 8);
        bf16x8 xf1 = ldb(X + (size_t)(mb + 16 + c) * DM_ + kc * 32 + g * 8);
#pragma unroll
        for (int n = 0; n < 4; n++) {
            const int oc = w * 64 + n * 16 + c;
            bf16x8 wf = ldb(Wb + (size_t)oc * DM_ + kc * 32 + g * 8);
            if (y == 2) {
                acc[0][n] = __builtin_amdgcn_mfma_f32_16x16x32_bf16(xf0, wf, acc[0][n], 0, 0, 0);
                acc[1][n] = __builtin_amdgcn_mfma_f32_16x16x32_bf16(xf1, wf, acc[1][n], 0, 0, 0);
            } else {
                acc[0][n] = __builtin_amdgcn_mfma_f32_16x16x32_bf16(wf, xf0, acc[0][n], 0, 0, 0);
                acc[1][n] = __builtin_amdgcn_mfma_f32_16x16x32_bf16(wf, xf1, acc[1][n], 0, 0, 0);
            }
        }
    }

    const int bhb = b * H_;
    if (y == 2) {
        // stage [d_global][l_local] fp16 in LDS, then row-copy to VT
#pragma unroll
        for (int s = 0; s < 2; s++)
#pragma unroll
            for (int n = 0; n < 4; n++) {
                int dg = w * 64 + (n >> 1) * 32 + (n & 1) * 16 + c;
                int ll = s * 16 + g * 4;
                float2 pr;
                pr.x = pkrtz(acc[s][n][0], acc[s][n][1]);
                pr.y = pkrtz(acc[s][n][2], acc[s][n][3]);
                *(float2*)(ldsV + (size_t)dg * 36 + ll) = pr;
            }
        __syncthreads();
        const int t = threadIdx.x;
        const int h = t >> 5, d = t & 31;
        f16* row = vo + ((size_t)(bhb + h) * DH_ + d) * (size_t)L + lb;
#pragma unroll
        for (int j = 0; j < 4; j++)
            *(f16x8*)(row + j * 8) = *(const f16x8*)(ldsV + (size_t)t * 36 + j * 8);
    } else {
        __bf16* out = (y == 0) ? qo : ko;
#pragma unroll
        for (int s = 0; s < 2; s++)
#pragma unroll
            for (int n = 0; n < 4; n++) {
                int dlo = (n & 1) * 16 + g * 4;
                int h = w * 2 + (n >> 1);
                int l = lb + s * 16 + c;
                *(bf16x4*)(out + ((size_t)(bhb + h) * (size_t)L + l) * DH_ + dlo) = pack4(acc[s][n]);
            }
    }
}

// ---- flash attention: 64 q/wave, fp16 P (pkrtz), h-paired 16KB LDS, split-K ----
__device__ __forceinline__ void attn_step(
    const bf16x8 (&qf)[4], const bf16x8 (&kf)[4], bf16x8 (&kfN)[4],
    const __bf16* __restrict__ knext,
    const f16* __restrict__ vb0, const f16* __restrict__ vb1, int kb,
    f16* __restrict__ Pw, int g, int c,
    float (&l)[4], floatx4 (&o)[4][2])
{
    f16x8 vf[4];
    vf[0] = *(const f16x8*)(vb0 + kb);
    vf[1] = *(const f16x8*)(vb1 + kb);
    vf[2] = *(const f16x8*)(vb0 + kb + 32);
    vf[3] = *(const f16x8*)(vb1 + kb + 32);
    kfN[0] = ldb(knext);
    kfN[1] = ldb(knext + 16 * DH_);
    kfN[2] = ldb(knext + 32 * DH_);
    kfN[3] = ldb(knext + 48 * DH_);

#pragma unroll
    for (int hp = 0; hp < 2; hp++) {
#pragma unroll
        for (int hh = 0; hh < 2; hh++) {
            const int h = hp * 2 + hh;
            floatx4 s[4];
#pragma unroll
            for (int st = 0; st < 4; st++)
                s[st] = __builtin_amdgcn_mfma_f32_16x16x32_bf16(
                            kf[st], qf[h], (floatx4){0.f, 0.f, 0.f, 0.f}, 0, 0, 0);
#pragma unroll
            for (int st = 0; st < 4; st++) {
                float e0 = __builtin_amdgcn_exp2f(s[st][0]);
                float e1 = __builtin_amdgcn_exp2f(s[st][1]);
                float e2 = __builtin_amdgcn_exp2f(s[st][2]);
                float e3 = __builtin_amdgcn_exp2f(s[st][3]);
                l[h] += (e0 + e1) + (e2 + e3);
                float2 pr;
                pr.x = pkrtz(e0, e1);
                pr.y = pkrtz(e2, e3);
                *(float2*)(Pw + hh * 1024 + ((st * 2 + (g >> 1)) * 16 + c) * 8 + (g & 1) * 4) = pr;
            }
        }
        // consume both P buffers of this h-pair (wave-private: in-order DS, no barrier)
#pragma unroll
        for (int kc = 0; kc < 2; kc++)
#pragma unroll
            for (int hh = 0; hh < 2; hh++) {
                const int h = hp * 2 + hh;
                f16x8 pa = *(const f16x8*)(Pw + hh * 1024 + ((kc * 4 + g) * 16 + c) * 8);
                o[h][0] = __builtin_amdgcn_mfma_f32_16x16x32_f16(pa, vf[kc * 2 + 0], o[h][0], 0, 0, 0);
                o[h][1] = __builtin_amdgcn_mfma_f32_16x16x32_f16(pa, vf[kc * 2 + 1], o[h][1], 0, 0, 0);
            }
    }
}

template<bool DIRECT>
__global__ __launch_bounds__(256, 2) void attn_kernel(
    const __bf16* __restrict__ Q, const __bf16* __restrict__ K,
    const f16* __restrict__ VT, float* __restrict__ out,
    f16* __restrict__ Opart, float* __restrict__ Lpart, int klen, int split)
{
    __shared__ f16 ldsP[4][2][1024];   // [wave][h-parity], wave-private, 16 KB

    const int bid  = blockIdx.x;
    const int work = (bid & 7) * (32 * split) + (bid >> 3);
    const int xb   = work & 15;
    const int bh   = (work >> 4) & 15;
    const int z    = work >> 8;

    const int lane  = threadIdx.x & 63;
    const int w     = threadIdx.x >> 6;
    const int g     = lane >> 4;
    const int c     = lane & 15;
    const int qbase = xb * 256 + w * 64;
    const int k0    = z * klen;

    bf16x8 qf[4];
#pragma unroll
    for (int h = 0; h < 4; h++)
        qf[h] = ldb(Q + ((size_t)bh * L1_ + qbase + h * 16 + c) * DH_ + g * 8);

    const __bf16* kbase = K  + (size_t)bh * L2_ * DH_ + (size_t)c * DH_ + g * 8;
    const f16*    vb0   = VT + ((size_t)bh * DH_ + c)      * L2_ + g * 8;
    const f16*    vb1   = VT + ((size_t)bh * DH_ + 16 + c) * L2_ + g * 8;
    f16* Pw = &ldsP[w][0][0];

    float l[4] = {0.f, 0.f, 0.f, 0.f};
    floatx4 o[4][2];
#pragma unroll
    for (int h = 0; h < 4; h++) { o[h][0] = (floatx4){0.f,0.f,0.f,0.f}; o[h][1] = (floatx4){0.f,0.f,0.f,0.f}; }

    bf16x8 kfA[4], kfB[4];
#pragma unroll
    for (int st = 0; st < 4; st++)
        kfA[st] = ldb(kbase + (size_t)(k0 + st * 16) * DH_);

    for (int t = 0; t < klen; t += 128) {
        int kb = k0 + t;
        attn_step(qf, kfA, kfB, kbase + (size_t)(kb + 64) * DH_,
                  vb0, vb1, kb, Pw, g, c, l, o);
        int nn = (t + 128 < klen) ? kb + 128 : k0;
        attn_step(qf, kfB, kfA, kbase + (size_t)nn * DH_,
                  vb0, vb1, kb + 64, Pw, g, c, l, o);
    }

#pragma unroll
    for (int h = 0; h < 4; h++) {
        l[h] += __shfl_xor(l[h], 16, 64);
        l[h] += __shfl_xor(l[h], 32, 64);
    }

    const int b  = bh / H_;
    const int hh = bh % H_;
    if (DIRECT) {
#pragma unroll
        for (int h = 0; h < 4; h++)
#pragma unroll
            for (int r = 0; r < 4; r++) {
                float lr  = __shfl(l[h], g * 4 + r, 64);
                float inv = 1.0f / lr;
                size_t base = ((size_t)(b * L1_ + qbase + h * 16 + g * 4 + r)) * DM_ + hh * DH_;
                out[base + c]      = o[h][0][r] * inv;
                out[base + 16 + c] = o[h][1][r] * inv;
            }
    } else {
        f16* Op = Opart + (size_t)z * ((size_t)B_ * L1_ * DM_);
#pragma unroll
        for (int h = 0; h < 4; h++) {
#pragma unroll
            for (int r = 0; r < 4; r++) {
                size_t base = ((size_t)(b * L1_ + qbase + h * 16 + g * 4 + r)) * DM_ + hh * DH_;
                Op[base + c]      = (f16)o[h][0][r];
                Op[base + 16 + c] = (f16)o[h][1][r];
            }
            if (g == 0)
                Lpart[(size_t)z * ((size_t)B_ * H_ * L1_) +
                      (size_t)bh * L1_ + qbase + h * 16 + c] = l[h];
        }
    }
}

// out = (sum_z Opart) / (sum_z Lpart)
__global__ __launch_bounds__(256) void combine_kernel(
    const f16* __restrict__ Opart, const float* __restrict__ Lpart,
    float* __restrict__ out, int split)
{
    int t   = blockIdx.x * 256 + threadIdx.x;
    int row = t >> 6;
    int col = (t & 63) * 4;
    int b   = row >> 12;
    int q   = row & (L1_ - 1);
    int bh  = b * H_ + (col >> 5);
    float4 a = {0.f, 0.f, 0.f, 0.f};
    float ls = 0.f;
    for (int z = 0; z < split; z++) {
        const f16* Op = Opart + (size_t)z * ((size_t)B_ * L1_ * DM_);
        f16x4 v = *(const f16x4*)(Op + (size_t)row * DM_ + col);
        a.x += (float)v[0]; a.y += (float)v[1];
        a.z += (float)v[2]; a.w += (float)v[3];
        ls += Lpart[(size_t)z * ((size_t)B_ * H_ * L1_) + (size_t)bh * L1_ + q];
    }
    float inv = 1.0f / ls;
    float4 r; r.x = a.x * inv; r.y = a.y * inv; r.z = a.z * inv; r.w = a.w * inv;
    *(float4*)(out + (size_t)row * DM_ + col) = r;
}

extern "C" void kernel_launch(void* const* d_in, const int* in_sizes, int n_in,
                              void* d_out, int out_size, void* d_ws, size_t ws_size,
                              hipStream_t stream) {
    const float* x   = (const float*)d_in[0];
    const float* src = (const float*)d_in[1];
    const float* Wq  = (const float*)d_in[2];
    const float* Wk  = (const float*)d_in[3];
    const float* Wv  = (const float*)d_in[4];
    float* out = (float*)d_out;

    const float qscale = 1.4426950408889634f / sqrtf((float)DH_); // log2e * Dh^-0.5

    const size_t nW = 3 * 65536;
    const size_t nQ = (size_t)B_ * H_ * L1_ * DH_;   // 2,097,152
    const size_t nK = (size_t)B_ * H_ * L2_ * DH_;   // 3,145,728
    const size_t nX = nQ;

    // persistent: [W | Q | K | VT], union region: phase1 xbf/sbf, phase2 Opart/Lpart
    __bf16* wbf = (__bf16*)d_ws;
    __bf16* qws = wbf + nW;
    __bf16* kws = qws + nQ;
    f16*    vt  = (f16*)(kws + nK);
    size_t unionOff = ((nW + nQ + 2 * nK) * 2 + 255) & ~(size_t)255;
    __bf16* xbf = (__bf16*)((char*)d_ws + unionOff);
    __bf16* sbf = xbf + nX;

    const size_t oPartB = (size_t)B_ * L1_ * DM_ * sizeof(f16);   // 4 MB / split
    const size_t lPartB = (size_t)B_ * H_ * L1_ * 4;              // 256 KB / split
    const size_t avail  = ws_size > unionOff ? ws_size - unionOff : 0;
    int split = 1;
    if      (avail >= 8 * (oPartB + lPartB)) split = 8;
    else if (avail >= 6 * (oPartB + lPartB)) split = 6;
    else if (avail >= 4 * (oPartB + lPartB)) split = 4;
    else if (avail >= 2 * (oPartB + lPartB)) split = 2;
    f16*   Opart = (f16*)((char*)d_ws + unionOff);
    float* Lpart = (float*)((char*)d_ws + unionOff + (size_t)split * oPartB);

    cvt_all<<<dim3(5312), 256, 0, stream>>>(Wq, Wk, Wv, x, src, wbf, xbf, sbf, qscale);
    proj_kernel<<<dim3(1024), 256, 0, stream>>>(xbf, sbf, wbf, qws, kws, vt);

    if (split > 1) {
        attn_kernel<false><<<dim3(256 * split), 256, 0, stream>>>(
            qws, kws, vt, nullptr, Opart, Lpart, L2_ / split, split);
        combine_kernel<<<dim3(2048), 256, 0, stream>>>(Opart, Lpart, out, split);
    } else {
        attn_kernel<true><<<dim3(256), 256, 0, stream>>>(
            qws, kws, vt, out, nullptr, nullptr, L2_, 1);
    }
}

// Round 14
// 178.819 us; speedup vs baseline: 2.3237x; 1.0532x over previous
//
#include <hip/hip_runtime.h>
#include <math.h>

#define B_   2
#define L1_  4096
#define L2_  6144
#define DM_  256
#define H_   8
#define DH_  32

// LDS layout (attn): K dbuf rows padded to 80 B, V dbuf rows padded to 144 B.
#define KROW 80
#define VROW 144
#define KBUF (64 * KROW)            // 5120 B
#define VBUF (32 * VROW)            // 4608 B
#define POFF (2 * KBUF + 2 * VBUF)  // 19456 B
#define LDSZ (POFF + 4 * 4096)      // 35840 B  (4096 B of P per wave — R13 bug was 2048)

typedef __bf16 bf16x8 __attribute__((ext_vector_type(8)));
typedef __bf16 bf16x4 __attribute__((ext_vector_type(4)));
typedef float floatx4 __attribute__((ext_vector_type(4)));
typedef _Float16 f16;
typedef _Float16 f16x4 __attribute__((ext_vector_type(4)));
typedef _Float16 f16x8 __attribute__((ext_vector_type(8)));
typedef __fp16 fp16v2 __attribute__((ext_vector_type(2)));   // cvt_pkrtz return type

__device__ __forceinline__ bf16x8 ldb(const __bf16* p) { return *(const bf16x8*)p; }

__device__ __forceinline__ bf16x4 pack4(floatx4 v) {
    bf16x4 r;
    r[0] = (__bf16)v[0]; r[1] = (__bf16)v[1];
    r[2] = (__bf16)v[2]; r[3] = (__bf16)v[3];
    return r;
}

__device__ __forceinline__ float pkrtz(float a, float b) {
    fp16v2 p = __builtin_amdgcn_cvt_pkrtz(a, b);
    return __builtin_bit_cast(float, p);
}

// ---- convert W (qscale folded into Wq), x, source to bf16. Pure bandwidth. ----
__global__ __launch_bounds__(256) void cvt_all(
    const float* __restrict__ wq, const float* __restrict__ wk,
    const float* __restrict__ wv, const float* __restrict__ x,
    const float* __restrict__ src,
    __bf16* __restrict__ wbf, __bf16* __restrict__ xbf, __bf16* __restrict__ sbf,
    float qscale)
{
    int i = blockIdx.x * 256 + threadIdx.x;
    const float* s; __bf16* d; float sc = 1.0f; size_t off;
    if (i < 49152) {
        int seg = i >> 14;
        off = (size_t)(i & 16383) * 4;
        s = seg == 0 ? wq : (seg == 1 ? wk : wv);
        d = wbf + (size_t)seg * 65536;
        if (seg == 0) sc = qscale;
    } else if (i < 49152 + 524288) {
        off = (size_t)(i - 49152) * 4; s = x; d = xbf;
    } else {
        off = (size_t)(i - 49152 - 524288) * 4; s = src; d = sbf;
    }
    float4 v = *(const float4*)(s + off);
    bf16x4 r;
    r[0] = (__bf16)(v.x * sc); r[1] = (__bf16)(v.y * sc);
    r[2] = (__bf16)(v.z * sc); r[3] = (__bf16)(v.w * sc);
    *(bf16x4*)(d + off) = r;
}

// ---- proj: all-bf16 GEMM; Q/K out bf16, V out fp16 (transposed via LDS). ----
__global__ __launch_bounds__(256) void proj_kernel(
    const __bf16* __restrict__ xbf, const __bf16* __restrict__ sbf,
    const __bf16* __restrict__ Wbf,
    __bf16* __restrict__ qo, __bf16* __restrict__ ko, f16* __restrict__ vo)
{
    __shared__ f16 ldsV[256 * 36];   // 18 KB, V blocks only

    const int bid = blockIdx.x;
    int y, xb;
    if      (bid < 256) { y = 0; xb = bid; }
    else if (bid < 640) { y = 1; xb = bid - 256; }
    else                { y = 2; xb = bid - 640; }

    const int L = (y == 0) ? L1_ : L2_;
    const __bf16* X   = (y == 0) ? xbf : sbf;
    const __bf16* Wb  = Wbf + (size_t)y * 65536;

    const int lane = threadIdx.x & 63;
    const int w    = threadIdx.x >> 6;
    const int g    = lane >> 4;
    const int c    = lane & 15;
    const int mb   = xb * 32;
    const int b    = mb / L;
    const int lb   = mb - b * L;

    floatx4 acc[2][4];
#pragma unroll
    for (int s = 0; s < 2; s++)
#pragma unroll
        for (int n = 0; n < 4; n++) acc[s][n] = (floatx4){0.f, 0.f, 0.f, 0.f};

#pragma unroll
    for (int kc = 0; kc < 8; kc++) {
        bf16x8 xf0 = ldb(X + (size_t)(mb + c) * DM_ + kc * 32 + g * 8);
        bf16x8 xf1 = ldb(X + (size_t)(mb + 16 + c) * DM_ + kc * 32 + g * 8);
#pragma unroll
        for (int n = 0; n < 4; n++) {
            const int oc = w * 64 + n * 16 + c;
            bf16x8 wf = ldb(Wb + (size_t)oc * DM_ + kc * 32 + g * 8);
            if (y == 2) {
                acc[0][n] = __builtin_amdgcn_mfma_f32_16x16x32_bf16(xf0, wf, acc[0][n], 0, 0, 0);
                acc[1][n] = __builtin_amdgcn_mfma_f32_16x16x32_bf16(xf1, wf, acc[1][n], 0, 0, 0);
            } else {
                acc[0][n] = __builtin_amdgcn_mfma_f32_16x16x32_bf16(wf, xf0, acc[0][n], 0, 0, 0);
                acc[1][n] = __builtin_amdgcn_mfma_f32_16x16x32_bf16(wf, xf1, acc[1][n], 0, 0, 0);
            }
        }
    }

    const int bhb = b * H_;
    if (y == 2) {
        // stage [d_global][l_local] fp16 in LDS, then row-copy to VT
#pragma unroll
        for (int s = 0; s < 2; s++)
#pragma unroll
            for (int n = 0; n < 4; n++) {
                int dg = w * 64 + (n >> 1) * 32 + (n & 1) * 16 + c;
                int ll = s * 16 + g * 4;
                float2 pr;
                pr.x = pkrtz(acc[s][n][0], acc[s][n][1]);
                pr.y = pkrtz(acc[s][n][2], acc[s][n][3]);
                *(float2*)(ldsV + (size_t)dg * 36 + ll) = pr;
            }
        __syncthreads();
        const int t = threadIdx.x;
        const int h = t >> 5, d = t & 31;
        f16* row = vo + ((size_t)(bhb + h) * DH_ + d) * (size_t)L + lb;
#pragma unroll
        for (int j = 0; j < 4; j++)
            *(f16x8*)(row + j * 8) = *(const f16x8*)(ldsV + (size_t)t * 36 + j * 8);
    } else {
        __bf16* out = (y == 0) ? qo : ko;
#pragma unroll
        for (int s = 0; s < 2; s++)
#pragma unroll
            for (int n = 0; n < 4; n++) {
                int dlo = (n & 1) * 16 + g * 4;
                int h = w * 2 + (n >> 1);
                int l = lb + s * 16 + c;
                *(bf16x4*)(out + ((size_t)(bhb + h) * (size_t)L + l) * DH_ + dlo) = pack4(acc[s][n]);
            }
    }
}

// ---- flash attention v6: 64 q/wave, fp16 P, split-K + cooperative LDS-staged
// ---- K/V (one 8KB stage per block per 64-k tile instead of 4x redundant
// ---- register loads; single barrier per tile; loads issued post-barrier so
// ---- the barrier's vmcnt-drain never waits on the prefetch). ----
template<bool DIRECT>
__global__ __launch_bounds__(256, 2) void attn_kernel(
    const __bf16* __restrict__ Q, const __bf16* __restrict__ K,
    const f16* __restrict__ VT, float* __restrict__ out,
    f16* __restrict__ Opart, float* __restrict__ Lpart, int klen, int split)
{
    __shared__ __align__(16) unsigned char lds[LDSZ];

    const int bid  = blockIdx.x;
    const int work = (bid & 7) * (32 * split) + (bid >> 3);
    const int xb   = work & 15;
    const int bh   = (work >> 4) & 15;
    const int z    = work >> 8;

    const int lane  = threadIdx.x & 63;
    const int w     = threadIdx.x >> 6;
    const int g     = lane >> 4;
    const int c     = lane & 15;
    const int qbase = xb * 256 + w * 64;
    const int k0    = z * klen;

    bf16x8 qf[4];
#pragma unroll
    for (int h = 0; h < 4; h++)
        qf[h] = ldb(Q + ((size_t)bh * L1_ + qbase + h * 16 + c) * DH_ + g * 8);

    // staging addresses: this thread's 16B of K (row w*16+lane/4, chunk lane%4)
    // and 16B of V (row d = w*8+lane/8, chunk lane%8)
    const int krow = w * 16 + (lane >> 2);
    const int kchk = lane & 3;
    const int vrow = w * 8 + (lane >> 3);
    const int vchk = lane & 7;
    const __bf16* kgbase = K  + ((size_t)bh * L2_ + krow) * DH_ + kchk * 8;
    const f16*    vgbase = VT + ((size_t)bh * DH_ + vrow) * L2_ + vchk * 8;
    unsigned char* dstK = lds + krow * KROW + kchk * 16;
    unsigned char* dstV = lds + 2 * KBUF + vrow * VROW + vchk * 16;
    f16* Pw = (f16*)(lds + POFF + w * 4096);   // 4096 B per wave (fixed stride)

    float l[4] = {0.f, 0.f, 0.f, 0.f};
    floatx4 o[4][2];
#pragma unroll
    for (int h = 0; h < 4; h++) { o[h][0] = (floatx4){0.f,0.f,0.f,0.f}; o[h][1] = (floatx4){0.f,0.f,0.f,0.f}; }

    // prologue: stage tile k0 into buffer 0
    {
        float4 kr = *(const float4*)(kgbase + (size_t)k0 * DH_);
        float4 vr = *(const float4*)(vgbase + k0);
        *(float4*)dstK = kr;
        *(float4*)dstV = vr;
    }

    int buf = 0;
#pragma unroll 1
    for (int t = 0; t < klen; t += 64) {
        __syncthreads();   // tile t staged; previous iter's reads of buf^1 done

        // issue next tile's global loads (land during compute, consumed at tile end)
        float4 kr, vr;
        const bool more = (t + 64) < klen;
        if (more) {
            kr = *(const float4*)(kgbase + (size_t)(k0 + t + 64) * DH_);
            vr = *(const float4*)(vgbase + (k0 + t + 64));
        }

        const unsigned char* bK = lds + buf * KBUF;
        const unsigned char* bV = lds + 2 * KBUF + buf * VBUF;
        bf16x8 kf[4];
#pragma unroll
        for (int st = 0; st < 4; st++)
            kf[st] = *(const bf16x8*)(bK + (st * 16 + c) * KROW + g * 16);
        f16x8 vf[4];
        vf[0] = *(const f16x8*)(bV + c * VROW + g * 16);
        vf[1] = *(const f16x8*)(bV + (16 + c) * VROW + g * 16);
        vf[2] = *(const f16x8*)(bV + c * VROW + 64 + g * 16);
        vf[3] = *(const f16x8*)(bV + (16 + c) * VROW + 64 + g * 16);

#pragma unroll
        for (int hp = 0; hp < 2; hp++) {
#pragma unroll
            for (int hh = 0; hh < 2; hh++) {
                const int h = hp * 2 + hh;
                floatx4 s[4];
#pragma unroll
                for (int st = 0; st < 4; st++)
                    s[st] = __builtin_amdgcn_mfma_f32_16x16x32_bf16(
                                kf[st], qf[h], (floatx4){0.f, 0.f, 0.f, 0.f}, 0, 0, 0);
#pragma unroll
                for (int st = 0; st < 4; st++) {
                    float e0 = __builtin_amdgcn_exp2f(s[st][0]);
                    float e1 = __builtin_amdgcn_exp2f(s[st][1]);
                    float e2 = __builtin_amdgcn_exp2f(s[st][2]);
                    float e3 = __builtin_amdgcn_exp2f(s[st][3]);
                    l[h] += (e0 + e1) + (e2 + e3);
                    float2 pr;
                    pr.x = pkrtz(e0, e1);
                    pr.y = pkrtz(e2, e3);
                    *(float2*)(Pw + hh * 1024 + ((st * 2 + (g >> 1)) * 16 + c) * 8 + (g & 1) * 4) = pr;
                }
            }
            // consume both P buffers of this h-pair (wave-private: in-order DS)
#pragma unroll
            for (int kc = 0; kc < 2; kc++)
#pragma unroll
                for (int hh = 0; hh < 2; hh++) {
                    const int h = hp * 2 + hh;
                    f16x8 pa = *(const f16x8*)(Pw + hh * 1024 + ((kc * 4 + g) * 16 + c) * 8);
                    o[h][0] = __builtin_amdgcn_mfma_f32_16x16x32_f16(pa, vf[kc * 2 + 0], o[h][0], 0, 0, 0);
                    o[h][1] = __builtin_amdgcn_mfma_f32_16x16x32_f16(pa, vf[kc * 2 + 1], o[h][1], 0, 0, 0);
                }
        }

        // write next tile into the other buffer (safe: peers' reads of buf^1
        // drained at this iteration's entry barrier)
        if (more) {
            *(float4*)(lds + (buf ^ 1) * KBUF + krow * KROW + kchk * 16) = kr;
            *(float4*)(lds + 2 * KBUF + (buf ^ 1) * VBUF + vrow * VROW + vchk * 16) = vr;
        }
        buf ^= 1;
    }

#pragma unroll
    for (int h = 0; h < 4; h++) {
        l[h] += __shfl_xor(l[h], 16, 64);
        l[h] += __shfl_xor(l[h], 32, 64);
    }

    const int b  = bh / H_;
    const int hh = bh % H_;
    if (DIRECT) {
#pragma unroll
        for (int h = 0; h < 4; h++)
#pragma unroll
            for (int r = 0; r < 4; r++) {
                float lr  = __shfl(l[h], g * 4 + r, 64);
                float inv = 1.0f / lr;
                size_t base = ((size_t)(b * L1_ + qbase + h * 16 + g * 4 + r)) * DM_ + hh * DH_;
                out[base + c]      = o[h][0][r] * inv;
                out[base + 16 + c] = o[h][1][r] * inv;
            }
    } else {
        f16* Op = Opart + (size_t)z * ((size_t)B_ * L1_ * DM_);
#pragma unroll
        for (int h = 0; h < 4; h++) {
#pragma unroll
            for (int r = 0; r < 4; r++) {
                size_t base = ((size_t)(b * L1_ + qbase + h * 16 + g * 4 + r)) * DM_ + hh * DH_;
                Op[base + c]      = (f16)o[h][0][r];
                Op[base + 16 + c] = (f16)o[h][1][r];
            }
            if (g == 0)
                Lpart[(size_t)z * ((size_t)B_ * H_ * L1_) +
                      (size_t)bh * L1_ + qbase + h * 16 + c] = l[h];
        }
    }
}

// out = (sum_z Opart) / (sum_z Lpart)
__global__ __launch_bounds__(256) void combine_kernel(
    const f16* __restrict__ Opart, const float* __restrict__ Lpart,
    float* __restrict__ out, int split)
{
    int t   = blockIdx.x * 256 + threadIdx.x;
    int row = t >> 6;
    int col = (t & 63) * 4;
    int b   = row >> 12;
    int q   = row & (L1_ - 1);
    int bh  = b * H_ + (col >> 5);
    float4 a = {0.f, 0.f, 0.f, 0.f};
    float ls = 0.f;
    for (int z = 0; z < split; z++) {
        const f16* Op = Opart + (size_t)z * ((size_t)B_ * L1_ * DM_);
        f16x4 v = *(const f16x4*)(Op + (size_t)row * DM_ + col);
        a.x += (float)v[0]; a.y += (float)v[1];
        a.z += (float)v[2]; a.w += (float)v[3];
        ls += Lpart[(size_t)z * ((size_t)B_ * H_ * L1_) + (size_t)bh * L1_ + q];
    }
    float inv = 1.0f / ls;
    float4 r; r.x = a.x * inv; r.y = a.y * inv; r.z = a.z * inv; r.w = a.w * inv;
    *(float4*)(out + (size_t)row * DM_ + col) = r;
}

extern "C" void kernel_launch(void* const* d_in, const int* in_sizes, int n_in,
                              void* d_out, int out_size, void* d_ws, size_t ws_size,
                              hipStream_t stream) {
    const float* x   = (const float*)d_in[0];
    const float* src = (const float*)d_in[1];
    const float* Wq  = (const float*)d_in[2];
    const float* Wk  = (const float*)d_in[3];
    const float* Wv  = (const float*)d_in[4];
    float* out = (float*)d_out;

    const float qscale = 1.4426950408889634f / sqrtf((float)DH_); // log2e * Dh^-0.5

    const size_t nW = 3 * 65536;
    const size_t nQ = (size_t)B_ * H_ * L1_ * DH_;   // 2,097,152
    const size_t nK = (size_t)B_ * H_ * L2_ * DH_;   // 3,145,728
    const size_t nX = nQ;

    // persistent: [W | Q | K | VT], union region: phase1 xbf/sbf, phase2 Opart/Lpart
    __bf16* wbf = (__bf16*)d_ws;
    __bf16* qws = wbf + nW;
    __bf16* kws = qws + nQ;
    f16*    vt  = (f16*)(kws + nK);
    size_t unionOff = ((nW + nQ + 2 * nK) * 2 + 255) & ~(size_t)255;
    __bf16* xbf = (__bf16*)((char*)d_ws + unionOff);
    __bf16* sbf = xbf + nX;

    const size_t oPartB = (size_t)B_ * L1_ * DM_ * sizeof(f16);   // 4 MB / split
    const size_t lPartB = (size_t)B_ * H_ * L1_ * 4;              // 256 KB / split
    const size_t avail  = ws_size > unionOff ? ws_size - unionOff : 0;
    int split = 1;
    if      (avail >= 8 * (oPartB + lPartB)) split = 8;
    else if (avail >= 6 * (oPartB + lPartB)) split = 6;
    else if (avail >= 4 * (oPartB + lPartB)) split = 4;
    else if (avail >= 2 * (oPartB + lPartB)) split = 2;
    f16*   Opart = (f16*)((char*)d_ws + unionOff);
    float* Lpart = (float*)((char*)d_ws + unionOff + (size_t)split * oPartB);

    cvt_all<<<dim3(5312), 256, 0, stream>>>(Wq, Wk, Wv, x, src, wbf, xbf, sbf, qscale);
    proj_kernel<<<dim3(1024), 256, 0, stream>>>(xbf, sbf, wbf, qws, kws, vt);

    if (split > 1) {
        attn_kernel<false><<<dim3(256 * split), 256, 0, stream>>>(
            qws, kws, vt, nullptr, Opart, Lpart, L2_ / split, split);
        combine_kernel<<<dim3(2048), 256, 0, stream>>>(Opart, Lpart, out, split);
    } else {
        attn_kernel<true><<<dim3(256), 256, 0, stream>>>(
            qws, kws, vt, out, nullptr, nullptr, L2_, 1);
    }
}

// Round 15
// 175.882 us; speedup vs baseline: 2.3625x; 1.0167x over previous
//
#include <hip/hip_runtime.h>
#include <math.h>

#define B_   2
#define L1_  4096
#define L2_  6144
#define DM_  256
#define H_   8
#define DH_  32

// LDS layout (attn): K dbuf rows padded to 80 B, V dbuf rows padded to 144 B.
#define KROW 80
#define VROW 144
#define KBUF (64 * KROW)            // 5120 B
#define VBUF (32 * VROW)            // 4608 B
#define POFF (2 * KBUF + 2 * VBUF)  // 19456 B
#define LDSZ (POFF + 4 * 4096)      // 35840 B

typedef __bf16 bf16x8 __attribute__((ext_vector_type(8)));
typedef __bf16 bf16x4 __attribute__((ext_vector_type(4)));
typedef float floatx4 __attribute__((ext_vector_type(4)));
typedef _Float16 f16;
typedef _Float16 f16x4 __attribute__((ext_vector_type(4)));
typedef _Float16 f16x8 __attribute__((ext_vector_type(8)));
typedef __fp16 fp16v2 __attribute__((ext_vector_type(2)));   // cvt_pkrtz return type

__device__ __forceinline__ bf16x8 ldb(const __bf16* p) { return *(const bf16x8*)p; }

__device__ __forceinline__ bf16x4 pack4(floatx4 v) {
    bf16x4 r;
    r[0] = (__bf16)v[0]; r[1] = (__bf16)v[1];
    r[2] = (__bf16)v[2]; r[3] = (__bf16)v[3];
    return r;
}

__device__ __forceinline__ float pkrtz(float a, float b) {
    fp16v2 p = __builtin_amdgcn_cvt_pkrtz(a, b);
    return __builtin_bit_cast(float, p);
}

// ---- convert W (qscale folded into Wq), x, source to bf16. Pure bandwidth. ----
__global__ __launch_bounds__(256) void cvt_all(
    const float* __restrict__ wq, const float* __restrict__ wk,
    const float* __restrict__ wv, const float* __restrict__ x,
    const float* __restrict__ src,
    __bf16* __restrict__ wbf, __bf16* __restrict__ xbf, __bf16* __restrict__ sbf,
    float qscale)
{
    int i = blockIdx.x * 256 + threadIdx.x;
    const float* s; __bf16* d; float sc = 1.0f; size_t off;
    if (i < 49152) {
        int seg = i >> 14;
        off = (size_t)(i & 16383) * 4;
        s = seg == 0 ? wq : (seg == 1 ? wk : wv);
        d = wbf + (size_t)seg * 65536;
        if (seg == 0) sc = qscale;
    } else if (i < 49152 + 524288) {
        off = (size_t)(i - 49152) * 4; s = x; d = xbf;
    } else {
        off = (size_t)(i - 49152 - 524288) * 4; s = src; d = sbf;
    }
    float4 v = *(const float4*)(s + off);
    bf16x4 r;
    r[0] = (__bf16)(v.x * sc); r[1] = (__bf16)(v.y * sc);
    r[2] = (__bf16)(v.z * sc); r[3] = (__bf16)(v.w * sc);
    *(bf16x4*)(d + off) = r;
}

// ---- proj: all-bf16 GEMM; Q/K out bf16, V out fp16 (transposed via LDS). ----
__global__ __launch_bounds__(256) void proj_kernel(
    const __bf16* __restrict__ xbf, const __bf16* __restrict__ sbf,
    const __bf16* __restrict__ Wbf,
    __bf16* __restrict__ qo, __bf16* __restrict__ ko, f16* __restrict__ vo)
{
    __shared__ f16 ldsV[256 * 36];   // 18 KB, V blocks only

    const int bid = blockIdx.x;
    int y, xb;
    if      (bid < 256) { y = 0; xb = bid; }
    else if (bid < 640) { y = 1; xb = bid - 256; }
    else                { y = 2; xb = bid - 640; }

    const int L = (y == 0) ? L1_ : L2_;
    const __bf16* X   = (y == 0) ? xbf : sbf;
    const __bf16* Wb  = Wbf + (size_t)y * 65536;

    const int lane = threadIdx.x & 63;
    const int w    = threadIdx.x >> 6;
    const int g    = lane >> 4;
    const int c    = lane & 15;
    const int mb   = xb * 32;
    const int b    = mb / L;
    const int lb   = mb - b * L;

    floatx4 acc[2][4];
#pragma unroll
    for (int s = 0; s < 2; s++)
#pragma unroll
        for (int n = 0; n < 4; n++) acc[s][n] = (floatx4){0.f, 0.f, 0.f, 0.f};

#pragma unroll
    for (int kc = 0; kc < 8; kc++) {
        bf16x8 xf0 = ldb(X + (size_t)(mb + c) * DM_ + kc * 32 + g * 8);
        bf16x8 xf1 = ldb(X + (size_t)(mb + 16 + c) * DM_ + kc * 32 + g * 8);
#pragma unroll
        for (int n = 0; n < 4; n++) {
            const int oc = w * 64 + n * 16 + c;
            bf16x8 wf = ldb(Wb + (size_t)oc * DM_ + kc * 32 + g * 8);
            if (y == 2) {
                acc[0][n] = __builtin_amdgcn_mfma_f32_16x16x32_bf16(xf0, wf, acc[0][n], 0, 0, 0);
                acc[1][n] = __builtin_amdgcn_mfma_f32_16x16x32_bf16(xf1, wf, acc[1][n], 0, 0, 0);
            } else {
                acc[0][n] = __builtin_amdgcn_mfma_f32_16x16x32_bf16(wf, xf0, acc[0][n], 0, 0, 0);
                acc[1][n] = __builtin_amdgcn_mfma_f32_16x16x32_bf16(wf, xf1, acc[1][n], 0, 0, 0);
            }
        }
    }

    const int bhb = b * H_;
    if (y == 2) {
        // stage [d_global][l_local] fp16 in LDS, then row-copy to VT
#pragma unroll
        for (int s = 0; s < 2; s++)
#pragma unroll
            for (int n = 0; n < 4; n++) {
                int dg = w * 64 + (n >> 1) * 32 + (n & 1) * 16 + c;
                int ll = s * 16 + g * 4;
                float2 pr;
                pr.x = pkrtz(acc[s][n][0], acc[s][n][1]);
                pr.y = pkrtz(acc[s][n][2], acc[s][n][3]);
                *(float2*)(ldsV + (size_t)dg * 36 + ll) = pr;
            }
        __syncthreads();
        const int t = threadIdx.x;
        const int h = t >> 5, d = t & 31;
        f16* row = vo + ((size_t)(bhb + h) * DH_ + d) * (size_t)L + lb;
#pragma unroll
        for (int j = 0; j < 4; j++)
            *(f16x8*)(row + j * 8) = *(const f16x8*)(ldsV + (size_t)t * 36 + j * 8);
    } else {
        __bf16* out = (y == 0) ? qo : ko;
#pragma unroll
        for (int s = 0; s < 2; s++)
#pragma unroll
            for (int n = 0; n < 4; n++) {
                int dlo = (n & 1) * 16 + g * 4;
                int h = w * 2 + (n >> 1);
                int l = lb + s * 16 + c;
                *(bf16x4*)(out + ((size_t)(bhb + h) * (size_t)L + l) * DH_ + dlo) = pack4(acc[s][n]);
            }
    }
}

// ---- flash attention v7: v6 (LDS-staged K/V) + l-row-sum via ones-MFMA.
// l[q] = P @ ones rides the matrix pipe; epilogue l lands in the exact
// register lane/reg that writes row q (C-layout row = g*4+r), no shuffles.
template<bool DIRECT>
__global__ __launch_bounds__(256, 2) void attn_kernel(
    const __bf16* __restrict__ Q, const __bf16* __restrict__ K,
    const f16* __restrict__ VT, float* __restrict__ out,
    f16* __restrict__ Opart, float* __restrict__ Lpart, int klen, int split)
{
    __shared__ __align__(16) unsigned char lds[LDSZ];

    const int bid  = blockIdx.x;
    const int work = (bid & 7) * (32 * split) + (bid >> 3);
    const int xb   = work & 15;
    const int bh   = (work >> 4) & 15;
    const int z    = work >> 8;

    const int lane  = threadIdx.x & 63;
    const int w     = threadIdx.x >> 6;
    const int g     = lane >> 4;
    const int c     = lane & 15;
    const int qbase = xb * 256 + w * 64;
    const int k0    = z * klen;

    bf16x8 qf[4];
#pragma unroll
    for (int h = 0; h < 4; h++)
        qf[h] = ldb(Q + ((size_t)bh * L1_ + qbase + h * 16 + c) * DH_ + g * 8);

    const int krow = w * 16 + (lane >> 2);
    const int kchk = lane & 3;
    const int vrow = w * 8 + (lane >> 3);
    const int vchk = lane & 7;
    const __bf16* kgbase = K  + ((size_t)bh * L2_ + krow) * DH_ + kchk * 8;
    const f16*    vgbase = VT + ((size_t)bh * DH_ + vrow) * L2_ + vchk * 8;
    unsigned char* dstK = lds + krow * KROW + kchk * 16;
    unsigned char* dstV = lds + 2 * KBUF + vrow * VROW + vchk * 16;
    f16* Pw = (f16*)(lds + POFF + w * 4096);

    const f16x8 ones = {(f16)1.f, (f16)1.f, (f16)1.f, (f16)1.f,
                        (f16)1.f, (f16)1.f, (f16)1.f, (f16)1.f};

    floatx4 lacc[4];   // l row-sum accumulator: lane(g,c) reg r = l[q = h*16+g*4+r]
    floatx4 o[4][2];
#pragma unroll
    for (int h = 0; h < 4; h++) {
        lacc[h] = (floatx4){0.f, 0.f, 0.f, 0.f};
        o[h][0] = (floatx4){0.f, 0.f, 0.f, 0.f};
        o[h][1] = (floatx4){0.f, 0.f, 0.f, 0.f};
    }

    // prologue: stage tile k0 into buffer 0
    {
        float4 kr = *(const float4*)(kgbase + (size_t)k0 * DH_);
        float4 vr = *(const float4*)(vgbase + k0);
        *(float4*)dstK = kr;
        *(float4*)dstV = vr;
    }

    int buf = 0;
#pragma unroll 1
    for (int t = 0; t < klen; t += 64) {
        __syncthreads();   // tile t staged; previous iter's reads of buf^1 done

        float4 kr, vr;
        const bool more = (t + 64) < klen;
        if (more) {
            kr = *(const float4*)(kgbase + (size_t)(k0 + t + 64) * DH_);
            vr = *(const float4*)(vgbase + (k0 + t + 64));
        }

        const unsigned char* bK = lds + buf * KBUF;
        const unsigned char* bV = lds + 2 * KBUF + buf * VBUF;
        bf16x8 kf[4];
#pragma unroll
        for (int st = 0; st < 4; st++)
            kf[st] = *(const bf16x8*)(bK + (st * 16 + c) * KROW + g * 16);
        f16x8 vf[4];
        vf[0] = *(const f16x8*)(bV + c * VROW + g * 16);
        vf[1] = *(const f16x8*)(bV + (16 + c) * VROW + g * 16);
        vf[2] = *(const f16x8*)(bV + c * VROW + 64 + g * 16);
        vf[3] = *(const f16x8*)(bV + (16 + c) * VROW + 64 + g * 16);

#pragma unroll
        for (int hp = 0; hp < 2; hp++) {
#pragma unroll
            for (int hh = 0; hh < 2; hh++) {
                const int h = hp * 2 + hh;
                floatx4 s[4];
#pragma unroll
                for (int st = 0; st < 4; st++)
                    s[st] = __builtin_amdgcn_mfma_f32_16x16x32_bf16(
                                kf[st], qf[h], (floatx4){0.f, 0.f, 0.f, 0.f}, 0, 0, 0);
#pragma unroll
                for (int st = 0; st < 4; st++) {
                    float e0 = __builtin_amdgcn_exp2f(s[st][0]);
                    float e1 = __builtin_amdgcn_exp2f(s[st][1]);
                    float e2 = __builtin_amdgcn_exp2f(s[st][2]);
                    float e3 = __builtin_amdgcn_exp2f(s[st][3]);
                    float2 pr;
                    pr.x = pkrtz(e0, e1);
                    pr.y = pkrtz(e2, e3);
                    *(float2*)(Pw + hh * 1024 + ((st * 2 + (g >> 1)) * 16 + c) * 8 + (g & 1) * 4) = pr;
                }
            }
            // consume both P buffers of this h-pair (wave-private: in-order DS)
#pragma unroll
            for (int kc = 0; kc < 2; kc++)
#pragma unroll
                for (int hh = 0; hh < 2; hh++) {
                    const int h = hp * 2 + hh;
                    f16x8 pa = *(const f16x8*)(Pw + hh * 1024 + ((kc * 4 + g) * 16 + c) * 8);
                    o[h][0] = __builtin_amdgcn_mfma_f32_16x16x32_f16(pa, vf[kc * 2 + 0], o[h][0], 0, 0, 0);
                    o[h][1] = __builtin_amdgcn_mfma_f32_16x16x32_f16(pa, vf[kc * 2 + 1], o[h][1], 0, 0, 0);
                    lacc[h] = __builtin_amdgcn_mfma_f32_16x16x32_f16(pa, ones,         lacc[h], 0, 0, 0);
                }
        }

        if (more) {
            *(float4*)(lds + (buf ^ 1) * KBUF + krow * KROW + kchk * 16) = kr;
            *(float4*)(lds + 2 * KBUF + (buf ^ 1) * VBUF + vrow * VROW + vchk * 16) = vr;
        }
        buf ^= 1;
    }

    const int b  = bh / H_;
    const int hh = bh % H_;
    if (DIRECT) {
#pragma unroll
        for (int h = 0; h < 4; h++)
#pragma unroll
            for (int r = 0; r < 4; r++) {
                float inv = 1.0f / lacc[h][r];
                size_t base = ((size_t)(b * L1_ + qbase + h * 16 + g * 4 + r)) * DM_ + hh * DH_;
                out[base + c]      = o[h][0][r] * inv;
                out[base + 16 + c] = o[h][1][r] * inv;
            }
    } else {
        f16* Op = Opart + (size_t)z * ((size_t)B_ * L1_ * DM_);
#pragma unroll
        for (int h = 0; h < 4; h++) {
#pragma unroll
            for (int r = 0; r < 4; r++) {
                size_t base = ((size_t)(b * L1_ + qbase + h * 16 + g * 4 + r)) * DM_ + hh * DH_;
                Op[base + c]      = (f16)o[h][0][r];
                Op[base + 16 + c] = (f16)o[h][1][r];
            }
            if (c == 0)   // l[q=g*4+r] lives in lacc[h][r] of every c; lane c==0 stores
#pragma unroll
                for (int r = 0; r < 4; r++)
                    Lpart[(size_t)z * ((size_t)B_ * H_ * L1_) +
                          (size_t)bh * L1_ + qbase + h * 16 + g * 4 + r] = lacc[h][r];
        }
    }
}

// out = (sum_z Opart) / (sum_z Lpart)
__global__ __launch_bounds__(256) void combine_kernel(
    const f16* __restrict__ Opart, const float* __restrict__ Lpart,
    float* __restrict__ out, int split)
{
    int t   = blockIdx.x * 256 + threadIdx.x;
    int row = t >> 6;
    int col = (t & 63) * 4;
    int b   = row >> 12;
    int q   = row & (L1_ - 1);
    int bh  = b * H_ + (col >> 5);
    float4 a = {0.f, 0.f, 0.f, 0.f};
    float ls = 0.f;
    for (int z = 0; z < split; z++) {
        const f16* Op = Opart + (size_t)z * ((size_t)B_ * L1_ * DM_);
        f16x4 v = *(const f16x4*)(Op + (size_t)row * DM_ + col);
        a.x += (float)v[0]; a.y += (float)v[1];
        a.z += (float)v[2]; a.w += (float)v[3];
        ls += Lpart[(size_t)z * ((size_t)B_ * H_ * L1_) + (size_t)bh * L1_ + q];
    }
    float inv = 1.0f / ls;
    float4 r; r.x = a.x * inv; r.y = a.y * inv; r.z = a.z * inv; r.w = a.w * inv;
    *(float4*)(out + (size_t)row * DM_ + col) = r;
}

extern "C" void kernel_launch(void* const* d_in, const int* in_sizes, int n_in,
                              void* d_out, int out_size, void* d_ws, size_t ws_size,
                              hipStream_t stream) {
    const float* x   = (const float*)d_in[0];
    const float* src = (const float*)d_in[1];
    const float* Wq  = (const float*)d_in[2];
    const float* Wk  = (const float*)d_in[3];
    const float* Wv  = (const float*)d_in[4];
    float* out = (float*)d_out;

    const float qscale = 1.4426950408889634f / sqrtf((float)DH_); // log2e * Dh^-0.5

    const size_t nW = 3 * 65536;
    const size_t nQ = (size_t)B_ * H_ * L1_ * DH_;   // 2,097,152
    const size_t nK = (size_t)B_ * H_ * L2_ * DH_;   // 3,145,728
    const size_t nX = nQ;

    // persistent: [W | Q | K | VT], union region: phase1 xbf/sbf, phase2 Opart/Lpart
    __bf16* wbf = (__bf16*)d_ws;
    __bf16* qws = wbf + nW;
    __bf16* kws = qws + nQ;
    f16*    vt  = (f16*)(kws + nK);
    size_t unionOff = ((nW + nQ + 2 * nK) * 2 + 255) & ~(size_t)255;
    __bf16* xbf = (__bf16*)((char*)d_ws + unionOff);
    __bf16* sbf = xbf + nX;

    const size_t oPartB = (size_t)B_ * L1_ * DM_ * sizeof(f16);   // 4 MB / split
    const size_t lPartB = (size_t)B_ * H_ * L1_ * 4;              // 256 KB / split
    const size_t avail  = ws_size > unionOff ? ws_size - unionOff : 0;
    int split = 1;
    if      (avail >= 8 * (oPartB + lPartB)) split = 8;
    else if (avail >= 6 * (oPartB + lPartB)) split = 6;
    else if (avail >= 4 * (oPartB + lPartB)) split = 4;
    else if (avail >= 2 * (oPartB + lPartB)) split = 2;
    f16*   Opart = (f16*)((char*)d_ws + unionOff);
    float* Lpart = (float*)((char*)d_ws + unionOff + (size_t)split * oPartB);

    cvt_all<<<dim3(5312), 256, 0, stream>>>(Wq, Wk, Wv, x, src, wbf, xbf, sbf, qscale);
    proj_kernel<<<dim3(1024), 256, 0, stream>>>(xbf, sbf, wbf, qws, kws, vt);

    if (split > 1) {
        attn_kernel<false><<<dim3(256 * split), 256, 0, stream>>>(
            qws, kws, vt, nullptr, Opart, Lpart, L2_ / split, split);
        combine_kernel<<<dim3(2048), 256, 0, stream>>>(Opart, Lpart, out, split);
    } else {
        attn_kernel<true><<<dim3(256), 256, 0, stream>>>(
            qws, kws, vt, out, nullptr, nullptr, L2_, 1);
    }
}